// Round 1
// baseline (111.636 us; speedup 1.0000x reference)
//
#include <hip/hip_runtime.h>
#include <hip/hip_bf16.h>
#include <math.h>

#define TAU_INV_LOG2E 14.4269504088896340736f  // (1/0.1) * log2(e)
#define EPS 1e-8f

typedef __attribute__((ext_vector_type(8))) short bf16x8;
typedef __attribute__((ext_vector_type(4))) float f32x4;

static __device__ __forceinline__ unsigned short f2bf(float f) {
    unsigned int u = __float_as_uint(f);
    unsigned int r = (u + 0x7fffu + ((u >> 16) & 1u)) >> 16;
    return (unsigned short)r;
}

static __device__ __forceinline__ void glds16(const void* g, void* l) {
    __builtin_amdgcn_global_load_lds(
        (const __attribute__((address_space(1))) unsigned int*)g,
        (__attribute__((address_space(3))) unsigned int*)l,
        16, 0, 0);
}

// Kernel 1: L2-normalize rows of x (N x 256 fp32) -> xn (bf16), zero rowsum.
// One wave per row; block = 256 threads = 4 rows.
__global__ __launch_bounds__(256) void normalize_kernel(
    const float* __restrict__ x, unsigned short* __restrict__ xn,
    float* __restrict__ rowsum, int N) {
    const int wave = threadIdx.x >> 6;
    const int lane = threadIdx.x & 63;
    const int row  = blockIdx.x * 4 + wave;
    if (row >= N) return;

    if (threadIdx.x < 4) {
        int rr = blockIdx.x * 4 + threadIdx.x;
        if (rr < N) rowsum[rr] = 0.0f;
    }

    const float4 v = ((const float4*)(x + (size_t)row * 256))[lane];
    float s = v.x * v.x + v.y * v.y + v.z * v.z + v.w * v.w;
    s += __shfl_xor(s, 1);
    s += __shfl_xor(s, 2);
    s += __shfl_xor(s, 4);
    s += __shfl_xor(s, 8);
    s += __shfl_xor(s, 16);
    s += __shfl_xor(s, 32);
    const float norm = fmaxf(sqrtf(s), 1e-12f);
    const float rinv = 1.0f / norm;

    ushort4 o;
    o.x = f2bf(v.x * rinv);
    o.y = f2bf(v.y * rinv);
    o.z = f2bf(v.z * rinv);
    o.w = f2bf(v.w * rinv);
    ((ushort4*)(xn + (size_t)row * 256))[lane] = o;
}

// Kernel 2: symmetric fused S = Xn*Xn^T on upper-triangle 128x128 tiles.
// exp(S/tau) with zero diagonal; off-diag tiles contribute row-sums AND
// col-sums (symmetry). Double-buffered LDS (2-phase): stage(t+1) is issued
// BEFORE compute(t), so the __syncthreads vmcnt(0) drain lands after the
// MFMA phase has covered the load latency (T3-minimum recipe).
__global__ __launch_bounds__(256, 2) void gemm_exp_rowsum_kernel(
    const unsigned short* __restrict__ xn, float* __restrict__ rowsum, int N) {
    const int D = 256;
    __shared__ unsigned short As[2][128 * 64];  // 2 x 16 KB
    __shared__ unsigned short Bs[2][128 * 64];  // 2 x 16 KB  (64 KB total)

    const int tid   = threadIdx.x;
    const int wave  = tid >> 6;
    const int lane  = tid & 63;
    const int waveM = wave >> 1;
    const int waveN = wave & 1;
    const int quad  = lane >> 4;
    const int l16   = lane & 15;

    // decode upper-triangle tile pair (bi <= bj) from 1D block index
    const int B = N >> 7;  // 64 tiles per dim
    const int t = blockIdx.x;
    int bi = (int)((2.0 * B + 1.0 -
                    sqrt((2.0 * B + 1.0) * (2.0 * B + 1.0) - 8.0 * (double)t)) * 0.5);
    while (bi > 0 && t < bi * B - (bi * (bi - 1)) / 2) --bi;
    while (t >= (bi + 1) * B - ((bi + 1) * bi) / 2) ++bi;
    const int bj = bi + (t - (bi * B - (bi * (bi - 1)) / 2));
    const bool diag = (bi == bj);

    const int iBase = bi * 128;
    const int jBase = bj * 128;

    f32x4 acc[4][4];
    #pragma unroll
    for (int mt = 0; mt < 4; ++mt)
        #pragma unroll
        for (int nt = 0; nt < 4; ++nt)
            acc[mt][nt] = (f32x4){0.f, 0.f, 0.f, 0.f};

    const int lrow = lane >> 3;            // 0..7 row within 8-row chunk
    const int lsw  = (lane & 7) ^ lrow;    // swizzled 16B col-chunk to fetch

    // stage one 128x64 K-slice of A (and B if off-diag) into buffer `buf`
    auto stage = [&](int buf, int k0) {
        #pragma unroll
        for (int it = 0; it < 4; ++it) {
            const int q   = wave * 4 + it;        // chunk 0..15
            const int row = q * 8 + lrow;         // 0..127
            glds16(xn + (size_t)(iBase + row) * D + k0 + lsw * 8,
                   &As[buf][q * 512]);
            if (!diag)
                glds16(xn + (size_t)(jBase + row) * D + k0 + lsw * 8,
                       &Bs[buf][q * 512]);
        }
    };

    // prologue: fill buffer 0, exposed drain (once per block)
    stage(0, 0);
    __syncthreads();

    #pragma unroll
    for (int kt = 0; kt < 4; ++kt) {
        const int cb = kt & 1;
        // issue next K-slice BEFORE compute: latency hides under MFMA phase
        if (kt < 3) stage(cb ^ 1, (kt + 1) * 64);

        const unsigned short* Ap = As[cb];
        const unsigned short* Bp = diag ? As[cb] : Bs[cb];
        #pragma unroll
        for (int kk = 0; kk < 64; kk += 32) {
            bf16x8 a[4], b[4];
            const int cA = (kk >> 3) + quad;      // 16B col-chunk index
            #pragma unroll
            for (int tt = 0; tt < 4; ++tt) {
                const int rA = waveM * 64 + tt * 16 + l16;
                a[tt] = *(const bf16x8*)(Ap + (rA >> 3) * 512 + (rA & 7) * 64 +
                                          ((cA ^ (rA & 7)) * 8));
                const int rB = waveN * 64 + tt * 16 + l16;
                b[tt] = *(const bf16x8*)(Bp + (rB >> 3) * 512 + (rB & 7) * 64 +
                                          ((cA ^ (rB & 7)) * 8));
            }
            #pragma unroll
            for (int mt = 0; mt < 4; ++mt)
                #pragma unroll
                for (int nt = 0; nt < 4; ++nt)
                    acc[mt][nt] = __builtin_amdgcn_mfma_f32_16x16x32_bf16(
                        a[mt], b[nt], acc[mt][nt], 0, 0, 0);
        }
        // one barrier per K-step: (a) everyone done reading buf cb before it
        // is re-staged at kt+2; (b) drains the in-flight loads for cb^1.
        // Last iteration needs neither (epilogue is register-only).
        if (kt < 3) __syncthreads();
    }

    // Epilogue. C/D layout: col = l16, row = quad*4 + reg  [m89/m91]
    float rsum[4][4];
    float csum[4] = {0.f, 0.f, 0.f, 0.f};
    #pragma unroll
    for (int mt = 0; mt < 4; ++mt)
        #pragma unroll
        for (int r = 0; r < 4; ++r) rsum[mt][r] = 0.f;

    #pragma unroll
    for (int mt = 0; mt < 4; ++mt) {
        const int gi0 = iBase + waveM * 64 + mt * 16 + quad * 4;
        #pragma unroll
        for (int nt = 0; nt < 4; ++nt) {
            const int gj = jBase + waveN * 64 + nt * 16 + l16;
            #pragma unroll
            for (int r = 0; r < 4; ++r) {
                float e = __builtin_amdgcn_exp2f(acc[mt][nt][r] * TAU_INV_LOG2E);
                if (gi0 + r == gj) e = 0.0f;  // diagonal (only on diag tiles)
                rsum[mt][r] += e;
                csum[nt] += e;
            }
        }
    }
    // row sums -> rowsum[i]
    #pragma unroll
    for (int mt = 0; mt < 4; ++mt) {
        const int gi0 = iBase + waveM * 64 + mt * 16 + quad * 4;
        #pragma unroll
        for (int r = 0; r < 4; ++r) {
            float s = rsum[mt][r];
            s += __shfl_xor(s, 1);
            s += __shfl_xor(s, 2);
            s += __shfl_xor(s, 4);
            s += __shfl_xor(s, 8);
            if (l16 == 0) atomicAdd(&rowsum[gi0 + r], s);
        }
    }
    // col sums -> rowsum[j] (symmetry), off-diag tiles only
    if (!diag) {
        #pragma unroll
        for (int nt = 0; nt < 4; ++nt) {
            float s = csum[nt];
            s += __shfl_xor(s, 16);
            s += __shfl_xor(s, 32);
            if (quad == 0)
                atomicAdd(&rowsum[jBase + waveN * 64 + nt * 16 + l16], s);
        }
    }
}

// Kernel 3: loss = mean_i log(rowsum_i/(N-1) + eps). Single block, 1024 thr.
__global__ __launch_bounds__(1024) void finalize_kernel(
    const float* __restrict__ rowsum, float* __restrict__ out, int N) {
    __shared__ float red[16];
    const float inv = 1.0f / (float)(N - 1);
    float acc = 0.f;
    const float4* r4 = (const float4*)rowsum;
    for (int i = threadIdx.x; i < (N >> 2); i += 1024) {
        const float4 v = r4[i];
        acc += logf(fmaf(v.x, inv, EPS)) + logf(fmaf(v.y, inv, EPS)) +
               logf(fmaf(v.z, inv, EPS)) + logf(fmaf(v.w, inv, EPS));
    }
    acc += __shfl_xor(acc, 1);
    acc += __shfl_xor(acc, 2);
    acc += __shfl_xor(acc, 4);
    acc += __shfl_xor(acc, 8);
    acc += __shfl_xor(acc, 16);
    acc += __shfl_xor(acc, 32);
    const int wave = threadIdx.x >> 6;
    const int lane = threadIdx.x & 63;
    if (lane == 0) red[wave] = acc;
    __syncthreads();
    if (threadIdx.x == 0) {
        float total = 0.f;
        #pragma unroll
        for (int w = 0; w < 16; ++w) total += red[w];
        out[0] = total / (float)N;
    }
}

extern "C" void kernel_launch(void* const* d_in, const int* in_sizes, int n_in,
                              void* d_out, int out_size, void* d_ws, size_t ws_size,
                              hipStream_t stream) {
    const float* x = (const float*)d_in[0];
    const int D = 256;
    const int N = in_sizes[0] / D;  // 8192

    unsigned short* xn = (unsigned short*)d_ws;  // N*D bf16 = 4 MB
    float* rowsum = (float*)((char*)d_ws + (size_t)N * D * sizeof(unsigned short));
    float* out = (float*)d_out;

    normalize_kernel<<<(N + 3) / 4, 256, 0, stream>>>(x, xn, rowsum, N);

    const int B = N / 128;
    const int T = B * (B + 1) / 2;  // 2080 upper-triangle tiles
    gemm_exp_rowsum_kernel<<<T, 256, 0, stream>>>(xn, rowsum, N);

    finalize_kernel<<<1, 1024, 0, stream>>>(rowsum, out, N);
}

// Round 2
// 104.117 us; speedup vs baseline: 1.0722x; 1.0722x over previous
//
#include <hip/hip_runtime.h>
#include <hip/hip_bf16.h>
#include <math.h>

#define TAU_INV_LOG2E 14.4269504088896340736f  // (1/0.1) * log2(e)
#define EPS 1e-8f

typedef __attribute__((ext_vector_type(8))) short bf16x8;
typedef __attribute__((ext_vector_type(4))) float f32x4;

static __device__ __forceinline__ unsigned short f2bf(float f) {
    unsigned int u = __float_as_uint(f);
    unsigned int r = (u + 0x7fffu + ((u >> 16) & 1u)) >> 16;
    return (unsigned short)r;
}

static __device__ __forceinline__ void glds16(const void* g, void* l) {
    __builtin_amdgcn_global_load_lds(
        (const __attribute__((address_space(1))) unsigned int*)g,
        (__attribute__((address_space(3))) unsigned int*)l,
        16, 0, 0);
}

// Kernel 1: L2-normalize rows of x (N x 256 fp32) -> xn (bf16), zero rowsum.
// One wave per row; block = 256 threads = 4 rows.
__global__ __launch_bounds__(256) void normalize_kernel(
    const float* __restrict__ x, unsigned short* __restrict__ xn,
    float* __restrict__ rowsum, int N) {
    const int wave = threadIdx.x >> 6;
    const int lane = threadIdx.x & 63;
    const int row  = blockIdx.x * 4 + wave;
    if (row >= N) return;

    if (threadIdx.x < 4) {
        int rr = blockIdx.x * 4 + threadIdx.x;
        if (rr < N) rowsum[rr] = 0.0f;
    }

    const float4 v = ((const float4*)(x + (size_t)row * 256))[lane];
    float s = v.x * v.x + v.y * v.y + v.z * v.z + v.w * v.w;
    s += __shfl_xor(s, 1);
    s += __shfl_xor(s, 2);
    s += __shfl_xor(s, 4);
    s += __shfl_xor(s, 8);
    s += __shfl_xor(s, 16);
    s += __shfl_xor(s, 32);
    const float norm = fmaxf(sqrtf(s), 1e-12f);
    const float rinv = 1.0f / norm;

    ushort4 o;
    o.x = f2bf(v.x * rinv);
    o.y = f2bf(v.y * rinv);
    o.z = f2bf(v.z * rinv);
    o.w = f2bf(v.w * rinv);
    ((ushort4*)(xn + (size_t)row * 256))[lane] = o;
}

// Kernel 2: symmetric fused S = Xn*Xn^T on upper-triangle 128x128 tiles.
// K-step = 32 with full double-buffering in the SAME 32 KB LDS footprint as
// the single-buffered K-step-64 version: stage(t+1) issued BEFORE compute(t),
// barrier at end of step drains it under the covered compute (T3-minimum),
// while occupancy stays at 3-4 blocks/CU.
// LDS layout per tile: row-linear [128][32] bf16 (64 B rows), 16B-chunk XOR
// swizzle c ^= (row>>1)&3 -> each 16-lane phase of ds_read_b128 is 2-way
// bank-aliased (free). global_load_lds source addresses are pre-swizzled so
// the linear DMA destination produces this layout (both-sides-or-neither).
__global__ __launch_bounds__(256, 3) void gemm_exp_rowsum_kernel(
    const unsigned short* __restrict__ xn, float* __restrict__ rowsum, int N) {
    const int D = 256;
    __shared__ unsigned short As[2][128 * 32];  // 2 x 8 KB
    __shared__ unsigned short Bs[2][128 * 32];  // 2 x 8 KB  (32 KB total)

    const int tid   = threadIdx.x;
    const int wave  = tid >> 6;
    const int lane  = tid & 63;
    const int waveM = wave >> 1;
    const int waveN = wave & 1;
    const int quad  = lane >> 4;
    const int l16   = lane & 15;

    // decode upper-triangle tile pair (bi <= bj) from 1D block index
    const int B = N >> 7;  // 64 tiles per dim
    const int t = blockIdx.x;
    int bi = (int)((2.0 * B + 1.0 -
                    sqrt((2.0 * B + 1.0) * (2.0 * B + 1.0) - 8.0 * (double)t)) * 0.5);
    while (bi > 0 && t < bi * B - (bi * (bi - 1)) / 2) --bi;
    while (t >= (bi + 1) * B - ((bi + 1) * bi) / 2) ++bi;
    const int bj = bi + (t - (bi * B - (bi * (bi - 1)) / 2));
    const bool diag = (bi == bj);

    const int iBase = bi * 128;
    const int jBase = bj * 128;

    f32x4 acc[4][4];
    #pragma unroll
    for (int mt = 0; mt < 4; ++mt)
        #pragma unroll
        for (int nt = 0; nt < 4; ++nt)
            acc[mt][nt] = (f32x4){0.f, 0.f, 0.f, 0.f};

    // staging: each wave DMAs 2 x 1KB chunks (16 rows x 32 cols each) per tile.
    // dest unit u = w*64 + lane -> row = 16w + (lane>>2), stored chunk = lane&3;
    // source data chunk = (lane&3) ^ ((row>>1)&3) = (lane&3) ^ ((lane>>3)&3).
    const int lrow4 = lane >> 2;                       // row within 16-row group
    const int csrc  = (lane & 3) ^ ((lane >> 3) & 3);  // pre-swizzled src chunk

    auto stage = [&](int buf, int k0) {
        #pragma unroll
        for (int it = 0; it < 2; ++it) {
            const int w = wave * 2 + it;       // wave-load index 0..7
            const int r = w * 16 + lrow4;      // row 0..127
            glds16(xn + (size_t)(iBase + r) * D + k0 + csrc * 8,
                   &As[buf][w * 512]);
            if (!diag)
                glds16(xn + (size_t)(jBase + r) * D + k0 + csrc * 8,
                       &Bs[buf][w * 512]);
        }
    };

    // ds_read offsets (shorts): row rA = waveM*64 + tt*16 + l16, chunk = quad.
    // stored chunk = quad ^ ((rA>>1)&3); (rA>>1)&3 == (l16>>1)&3 (base % 16 == 0)
    const int swz  = (quad ^ ((l16 >> 1) & 3)) * 8;
    const int offA = (waveM * 64 + l16) * 32 + swz;
    const int offB = (waveN * 64 + l16) * 32 + swz;
    const unsigned short* Bbase = diag ? &As[0][0] : &Bs[0][0];

    // prologue: fill buffer 0, exposed drain (once per block)
    stage(0, 0);
    __syncthreads();

    #pragma unroll
    for (int kt = 0; kt < 8; ++kt) {
        const int cb = kt & 1;
        // issue next K-slice BEFORE compute: its vmcnt drain at the end-of-step
        // barrier is covered by the ds_read + MFMA below.
        if (kt < 7) stage(cb ^ 1, (kt + 1) * 32);

        const unsigned short* Ap = &As[cb][0];
        const unsigned short* Bp = Bbase + cb * (128 * 32);
        bf16x8 a[4], b[4];
        #pragma unroll
        for (int tt = 0; tt < 4; ++tt) {
            a[tt] = *(const bf16x8*)(Ap + offA + tt * 512);
            b[tt] = *(const bf16x8*)(Bp + offB + tt * 512);
        }
        #pragma unroll
        for (int mt = 0; mt < 4; ++mt)
            #pragma unroll
            for (int nt = 0; nt < 4; ++nt)
                acc[mt][nt] = __builtin_amdgcn_mfma_f32_16x16x32_bf16(
                    a[mt], b[nt], acc[mt][nt], 0, 0, 0);

        // one barrier per step: (a) all waves done reading buf cb before it is
        // re-staged at kt+1; (b) drains in-flight loads for buf cb^1.
        if (kt < 7) __syncthreads();
    }

    // Epilogue. C/D layout: col = l16, row = quad*4 + reg  [m89/m91]
    float rsum[4][4];
    float csum[4] = {0.f, 0.f, 0.f, 0.f};
    #pragma unroll
    for (int mt = 0; mt < 4; ++mt)
        #pragma unroll
        for (int r = 0; r < 4; ++r) rsum[mt][r] = 0.f;

    #pragma unroll
    for (int mt = 0; mt < 4; ++mt) {
        const int gi0 = iBase + waveM * 64 + mt * 16 + quad * 4;
        #pragma unroll
        for (int nt = 0; nt < 4; ++nt) {
            const int gj = jBase + waveN * 64 + nt * 16 + l16;
            #pragma unroll
            for (int r = 0; r < 4; ++r) {
                float e = __builtin_amdgcn_exp2f(acc[mt][nt][r] * TAU_INV_LOG2E);
                if (gi0 + r == gj) e = 0.0f;  // diagonal (only on diag tiles)
                rsum[mt][r] += e;
                csum[nt] += e;
            }
        }
    }
    // row sums -> rowsum[i]
    #pragma unroll
    for (int mt = 0; mt < 4; ++mt) {
        const int gi0 = iBase + waveM * 64 + mt * 16 + quad * 4;
        #pragma unroll
        for (int r = 0; r < 4; ++r) {
            float s = rsum[mt][r];
            s += __shfl_xor(s, 1);
            s += __shfl_xor(s, 2);
            s += __shfl_xor(s, 4);
            s += __shfl_xor(s, 8);
            if (l16 == 0) atomicAdd(&rowsum[gi0 + r], s);
        }
    }
    // col sums -> rowsum[j] (symmetry), off-diag tiles only
    if (!diag) {
        #pragma unroll
        for (int nt = 0; nt < 4; ++nt) {
            float s = csum[nt];
            s += __shfl_xor(s, 16);
            s += __shfl_xor(s, 32);
            if (quad == 0)
                atomicAdd(&rowsum[jBase + waveN * 64 + nt * 16 + l16], s);
        }
    }
}

// Kernel 3: loss = mean_i log(rowsum_i/(N-1) + eps). Single block, 1024 thr.
__global__ __launch_bounds__(1024) void finalize_kernel(
    const float* __restrict__ rowsum, float* __restrict__ out, int N) {
    __shared__ float red[16];
    const float inv = 1.0f / (float)(N - 1);
    float acc = 0.f;
    const float4* r4 = (const float4*)rowsum;
    for (int i = threadIdx.x; i < (N >> 2); i += 1024) {
        const float4 v = r4[i];
        acc += logf(fmaf(v.x, inv, EPS)) + logf(fmaf(v.y, inv, EPS)) +
               logf(fmaf(v.z, inv, EPS)) + logf(fmaf(v.w, inv, EPS));
    }
    acc += __shfl_xor(acc, 1);
    acc += __shfl_xor(acc, 2);
    acc += __shfl_xor(acc, 4);
    acc += __shfl_xor(acc, 8);
    acc += __shfl_xor(acc, 16);
    acc += __shfl_xor(acc, 32);
    const int wave = threadIdx.x >> 6;
    const int lane = threadIdx.x & 63;
    if (lane == 0) red[wave] = acc;
    __syncthreads();
    if (threadIdx.x == 0) {
        float total = 0.f;
        #pragma unroll
        for (int w = 0; w < 16; ++w) total += red[w];
        out[0] = total / (float)N;
    }
}

extern "C" void kernel_launch(void* const* d_in, const int* in_sizes, int n_in,
                              void* d_out, int out_size, void* d_ws, size_t ws_size,
                              hipStream_t stream) {
    const float* x = (const float*)d_in[0];
    const int D = 256;
    const int N = in_sizes[0] / D;  // 8192

    unsigned short* xn = (unsigned short*)d_ws;  // N*D bf16 = 4 MB
    float* rowsum = (float*)((char*)d_ws + (size_t)N * D * sizeof(unsigned short));
    float* out = (float*)d_out;

    normalize_kernel<<<(N + 3) / 4, 256, 0, stream>>>(x, xn, rowsum, N);

    const int B = N / 128;
    const int T = B * (B + 1) / 2;  // 2080 upper-triangle tiles
    gemm_exp_rowsum_kernel<<<T, 256, 0, stream>>>(xn, rowsum, N);

    finalize_kernel<<<1, 1024, 0, stream>>>(rowsum, out, N);
}

// Round 3
// 95.839 us; speedup vs baseline: 1.1648x; 1.0864x over previous
//
#include <hip/hip_runtime.h>
#include <hip/hip_bf16.h>
#include <math.h>

#define TAU_INV_LOG2E 14.4269504088896340736f  // (1/0.1) * log2(e)
#define EPS 1e-8f

typedef __attribute__((ext_vector_type(8))) short bf16x8;
typedef __attribute__((ext_vector_type(4))) float f32x4;

static __device__ __forceinline__ unsigned short f2bf(float f) {
    unsigned int u = __float_as_uint(f);
    unsigned int r = (u + 0x7fffu + ((u >> 16) & 1u)) >> 16;
    return (unsigned short)r;
}

static __device__ __forceinline__ void glds16(const void* g, void* l) {
    __builtin_amdgcn_global_load_lds(
        (const __attribute__((address_space(1))) unsigned int*)g,
        (__attribute__((address_space(3))) unsigned int*)l,
        16, 0, 0);
}

// Kernel 1: L2-normalize rows of x (N x 256 fp32) -> xn (bf16). Zero out[0].
// One wave per row; block = 256 threads = 4 rows.
__global__ __launch_bounds__(256) void normalize_kernel(
    const float* __restrict__ x, unsigned short* __restrict__ xn,
    float* __restrict__ out, int N) {
    const int wave = threadIdx.x >> 6;
    const int lane = threadIdx.x & 63;
    const int row  = blockIdx.x * 4 + wave;
    if (row >= N) return;

    if (blockIdx.x == 0 && threadIdx.x == 0) out[0] = 0.0f;

    const float4 v = ((const float4*)(x + (size_t)row * 256))[lane];
    float s = v.x * v.x + v.y * v.y + v.z * v.z + v.w * v.w;
    s += __shfl_xor(s, 1);
    s += __shfl_xor(s, 2);
    s += __shfl_xor(s, 4);
    s += __shfl_xor(s, 8);
    s += __shfl_xor(s, 16);
    s += __shfl_xor(s, 32);
    const float norm = fmaxf(sqrtf(s), 1e-12f);
    const float rinv = 1.0f / norm;

    ushort4 o;
    o.x = f2bf(v.x * rinv);
    o.y = f2bf(v.y * rinv);
    o.z = f2bf(v.z * rinv);
    o.w = f2bf(v.w * rinv);
    ((ushort4*)(xn + (size_t)row * 256))[lane] = o;
}

// Kernel 2: symmetric fused S = Xn*Xn^T on upper-triangle 128x128 tiles.
// exp(S/tau), zero diagonal. NO ATOMICS: each block stores its row-partials
// and col-partials (symmetry) into a privately-owned slot of Prow[128][N]:
//   row-partials of tile bi  -> slot 2*bj + waveN
//   col-partials of tile bj  -> slot 2*bi + waveM   (off-diag only)
// Coverage proof: for target row-block a and slot s2 = 2s+b:
//   a <  s: written by block (a,s) row-partial, waveN=b
//   a >  s: written by block (s,a) col-partial, waveM=b
//   a == s: written by diag block (a,a) row-partial, waveN=b
// -> every cell written exactly once, no zero-init, no collisions.
__global__ __launch_bounds__(256, 3) void gemm_exp_rowsum_kernel(
    const unsigned short* __restrict__ xn, float* __restrict__ prow, int N) {
    const int D = 256;
    __shared__ unsigned short As[2][128 * 32];  // 2 x 8 KB
    __shared__ unsigned short Bs[2][128 * 32];  // 2 x 8 KB  (32 KB total)

    const int tid   = threadIdx.x;
    const int wave  = tid >> 6;
    const int lane  = tid & 63;
    const int waveM = wave >> 1;
    const int waveN = wave & 1;
    const int quad  = lane >> 4;
    const int l16   = lane & 15;

    // decode upper-triangle tile pair (bi <= bj) from 1D block index
    const int B = N >> 7;  // 64 tiles per dim
    const int t = blockIdx.x;
    int bi = (int)((2.0 * B + 1.0 -
                    sqrt((2.0 * B + 1.0) * (2.0 * B + 1.0) - 8.0 * (double)t)) * 0.5);
    while (bi > 0 && t < bi * B - (bi * (bi - 1)) / 2) --bi;
    while (t >= (bi + 1) * B - ((bi + 1) * bi) / 2) ++bi;
    const int bj = bi + (t - (bi * B - (bi * (bi - 1)) / 2));
    const bool diag = (bi == bj);

    const int iBase = bi * 128;
    const int jBase = bj * 128;

    f32x4 acc[4][4];
    #pragma unroll
    for (int mt = 0; mt < 4; ++mt)
        #pragma unroll
        for (int nt = 0; nt < 4; ++nt)
            acc[mt][nt] = (f32x4){0.f, 0.f, 0.f, 0.f};

    // staging: each wave DMAs 2 x 1KB chunks (16 rows x 32 cols each) per tile.
    const int lrow4 = lane >> 2;                       // row within 16-row group
    const int csrc  = (lane & 3) ^ ((lane >> 3) & 3);  // pre-swizzled src chunk

    auto stage = [&](int buf, int k0) {
        #pragma unroll
        for (int it = 0; it < 2; ++it) {
            const int w = wave * 2 + it;       // wave-load index 0..7
            const int r = w * 16 + lrow4;      // row 0..127
            glds16(xn + (size_t)(iBase + r) * D + k0 + csrc * 8,
                   &As[buf][w * 512]);
            if (!diag)
                glds16(xn + (size_t)(jBase + r) * D + k0 + csrc * 8,
                       &Bs[buf][w * 512]);
        }
    };

    // ds_read offsets (shorts): row rA = waveM*64 + tt*16 + l16, chunk = quad.
    const int swz  = (quad ^ ((l16 >> 1) & 3)) * 8;
    const int offA = (waveM * 64 + l16) * 32 + swz;
    const int offB = (waveN * 64 + l16) * 32 + swz;
    const unsigned short* Bbase = diag ? &As[0][0] : &Bs[0][0];

    // prologue: fill buffer 0, exposed drain (once per block)
    stage(0, 0);
    __syncthreads();

    #pragma unroll
    for (int kt = 0; kt < 8; ++kt) {
        const int cb = kt & 1;
        if (kt < 7) stage(cb ^ 1, (kt + 1) * 32);

        const unsigned short* Ap = &As[cb][0];
        const unsigned short* Bp = Bbase + cb * (128 * 32);
        bf16x8 a[4], b[4];
        #pragma unroll
        for (int tt = 0; tt < 4; ++tt) {
            a[tt] = *(const bf16x8*)(Ap + offA + tt * 512);
            b[tt] = *(const bf16x8*)(Bp + offB + tt * 512);
        }
        #pragma unroll
        for (int mt = 0; mt < 4; ++mt)
            #pragma unroll
            for (int nt = 0; nt < 4; ++nt)
                acc[mt][nt] = __builtin_amdgcn_mfma_f32_16x16x32_bf16(
                    a[mt], b[nt], acc[mt][nt], 0, 0, 0);

        if (kt < 7) __syncthreads();
    }

    // Epilogue. C/D layout: col = l16, row = quad*4 + reg  [m89/m91]
    float rsum[4][4];
    float csum[4] = {0.f, 0.f, 0.f, 0.f};
    #pragma unroll
    for (int mt = 0; mt < 4; ++mt)
        #pragma unroll
        for (int r = 0; r < 4; ++r) rsum[mt][r] = 0.f;

    #pragma unroll
    for (int mt = 0; mt < 4; ++mt) {
        const int gi0 = iBase + waveM * 64 + mt * 16 + quad * 4;
        #pragma unroll
        for (int nt = 0; nt < 4; ++nt) {
            const int gj = jBase + waveN * 64 + nt * 16 + l16;
            #pragma unroll
            for (int r = 0; r < 4; ++r) {
                float e = __builtin_amdgcn_exp2f(acc[mt][nt][r] * TAU_INV_LOG2E);
                if (gi0 + r == gj) e = 0.0f;  // diagonal (only on diag tiles)
                rsum[mt][r] += e;
                csum[nt] += e;
            }
        }
    }
    // row partials (this wave covers its waveN 64-col half) -> slot 2*bj+waveN
    {
        float* slot = prow + (size_t)(2 * bj + waveN) * N;
        #pragma unroll
        for (int mt = 0; mt < 4; ++mt) {
            const int gi0 = iBase + waveM * 64 + mt * 16 + quad * 4;
            #pragma unroll
            for (int r = 0; r < 4; ++r) {
                float s = rsum[mt][r];
                s += __shfl_xor(s, 1);
                s += __shfl_xor(s, 2);
                s += __shfl_xor(s, 4);
                s += __shfl_xor(s, 8);
                if (l16 == 0) slot[gi0 + r] = s;
            }
        }
    }
    // col partials (this wave covers its waveM 64-row half) -> slot 2*bi+waveM
    if (!diag) {
        float* slot = prow + (size_t)(2 * bi + waveM) * N;
        #pragma unroll
        for (int nt = 0; nt < 4; ++nt) {
            float s = csum[nt];
            s += __shfl_xor(s, 16);
            s += __shfl_xor(s, 32);
            if (quad == 0)
                slot[jBase + waveN * 64 + nt * 16 + l16] = s;
        }
    }
}

// Kernel 3: rowsum_i = sum_p Prow[p][i]; loss += log(rowsum/(N-1)+eps)/N.
// 32 blocks x 256 threads = one thread per row; reads coalesced across lanes.
__global__ __launch_bounds__(256) void finalize_kernel(
    const float* __restrict__ prow, float* __restrict__ out, int N) {
    __shared__ float red[4];
    const int i = blockIdx.x * 256 + threadIdx.x;
    const float inv = 1.0f / (float)(N - 1);
    float s = 0.f;
    #pragma unroll 16
    for (int p = 0; p < 128; ++p) s += prow[(size_t)p * N + i];
    float acc = logf(fmaf(s, inv, EPS));
    acc += __shfl_xor(acc, 1);
    acc += __shfl_xor(acc, 2);
    acc += __shfl_xor(acc, 4);
    acc += __shfl_xor(acc, 8);
    acc += __shfl_xor(acc, 16);
    acc += __shfl_xor(acc, 32);
    const int wave = threadIdx.x >> 6;
    const int lane = threadIdx.x & 63;
    if (lane == 0) red[wave] = acc;
    __syncthreads();
    if (threadIdx.x == 0) {
        float total = red[0] + red[1] + red[2] + red[3];
        atomicAdd(out, total / (float)N);  // 32 atomics total
    }
}

extern "C" void kernel_launch(void* const* d_in, const int* in_sizes, int n_in,
                              void* d_out, int out_size, void* d_ws, size_t ws_size,
                              hipStream_t stream) {
    const float* x = (const float*)d_in[0];
    const int D = 256;
    const int N = in_sizes[0] / D;  // 8192

    unsigned short* xn = (unsigned short*)d_ws;  // N*D bf16 = 4 MB
    float* prow = (float*)((char*)d_ws + (size_t)N * D * sizeof(unsigned short));
    // Prow: 128 x N fp32 = 4 MB
    float* out = (float*)d_out;

    normalize_kernel<<<(N + 3) / 4, 256, 0, stream>>>(x, xn, out, N);

    const int B = N / 128;
    const int T = B * (B + 1) / 2;  // 2080 upper-triangle tiles
    gemm_exp_rowsum_kernel<<<T, 256, 0, stream>>>(xn, prow, N);

    finalize_kernel<<<N / 256, 256, 0, stream>>>(prow, out, N);
}

// Round 4
// 95.314 us; speedup vs baseline: 1.1712x; 1.0055x over previous
//
#include <hip/hip_runtime.h>
#include <hip/hip_bf16.h>
#include <math.h>

#define TAU_INV_LOG2E 14.4269504088896340736f  // (1/0.1) * log2(e)
#define EPS 1e-8f

typedef __attribute__((ext_vector_type(8))) short bf16x8;
typedef __attribute__((ext_vector_type(4))) float f32x4;

#define WAITCNT_VM4()   asm volatile("s_waitcnt vmcnt(4)" ::: "memory")
#define WAITCNT_VM0()   asm volatile("s_waitcnt vmcnt(0)" ::: "memory")
#define WAITCNT_LGKM0() asm volatile("s_waitcnt lgkmcnt(0)" ::: "memory")
#define SCHED_FENCE()   __builtin_amdgcn_sched_barrier(0)

static __device__ __forceinline__ unsigned short f2bf(float f) {
    unsigned int u = __float_as_uint(f);
    unsigned int r = (u + 0x7fffu + ((u >> 16) & 1u)) >> 16;
    return (unsigned short)r;
}

static __device__ __forceinline__ void glds16(const void* g, void* l) {
    __builtin_amdgcn_global_load_lds(
        (const __attribute__((address_space(1))) unsigned int*)g,
        (__attribute__((address_space(3))) unsigned int*)l,
        16, 0, 0);
}

// Kernel 1: L2-normalize rows of x (N x 256 fp32) -> xn (bf16). Zero out[0].
__global__ __launch_bounds__(256) void normalize_kernel(
    const float* __restrict__ x, unsigned short* __restrict__ xn,
    float* __restrict__ out, int N) {
    const int wave = threadIdx.x >> 6;
    const int lane = threadIdx.x & 63;
    const int row  = blockIdx.x * 4 + wave;
    if (row >= N) return;

    if (blockIdx.x == 0 && threadIdx.x == 0) out[0] = 0.0f;

    const float4 v = ((const float4*)(x + (size_t)row * 256))[lane];
    float s = v.x * v.x + v.y * v.y + v.z * v.z + v.w * v.w;
    s += __shfl_xor(s, 1);
    s += __shfl_xor(s, 2);
    s += __shfl_xor(s, 4);
    s += __shfl_xor(s, 8);
    s += __shfl_xor(s, 16);
    s += __shfl_xor(s, 32);
    const float norm = fmaxf(sqrtf(s), 1e-12f);
    const float rinv = 1.0f / norm;

    ushort4 o;
    o.x = f2bf(v.x * rinv);
    o.y = f2bf(v.y * rinv);
    o.z = f2bf(v.z * rinv);
    o.w = f2bf(v.w * rinv);
    ((ushort4*)(xn + (size_t)row * 256))[lane] = o;
}

// Kernel 2: symmetric fused S = Xn*Xn^T, upper-triangle 128x128 tiles.
// T4 structure: 3-buffer ring, pipeline depth 2 (tiles t+1 AND t+2 in flight
// while computing t). End-of-step sync = lgkmcnt(0) + COUNTED vmcnt(4) (tile
// t+2's 4 loads never drained) + raw s_barrier. Staging is wave-uniform
// (diag tiles stage B redundantly) so vmcnt immediates are exact.
// Buffer written at step t is (t+2)%3 != t%3, (t+1)%3; ds_reads of it
// completed a barrier earlier (explicit lgkmcnt(0)).
// Atomic-free epilogue: partials to privately-owned slots of Prow[128][N].
__global__ __launch_bounds__(256, 3) void gemm_exp_rowsum_kernel(
    const unsigned short* __restrict__ xn, float* __restrict__ prow, int N) {
    const int D = 256;
    __shared__ unsigned short As[3][128 * 32];  // 3 x 8 KB
    __shared__ unsigned short Bs[3][128 * 32];  // 3 x 8 KB  (48 KB total)

    const int tid   = threadIdx.x;
    const int wave  = tid >> 6;
    const int lane  = tid & 63;
    const int waveM = wave >> 1;
    const int waveN = wave & 1;
    const int quad  = lane >> 4;
    const int l16   = lane & 15;

    // decode upper-triangle tile pair (bi <= bj) from 1D block index
    const int B = N >> 7;  // 64 tiles per dim
    const int t = blockIdx.x;
    int bi = (int)((2.0 * B + 1.0 -
                    sqrt((2.0 * B + 1.0) * (2.0 * B + 1.0) - 8.0 * (double)t)) * 0.5);
    while (bi > 0 && t < bi * B - (bi * (bi - 1)) / 2) --bi;
    while (t >= (bi + 1) * B - ((bi + 1) * bi) / 2) ++bi;
    const int bj = bi + (t - (bi * B - (bi * (bi - 1)) / 2));
    const bool diag = (bi == bj);

    const int iBase = bi * 128;
    const int jBase = bj * 128;

    f32x4 acc[4][4];
    #pragma unroll
    for (int mt = 0; mt < 4; ++mt)
        #pragma unroll
        for (int nt = 0; nt < 4; ++nt)
            acc[mt][nt] = (f32x4){0.f, 0.f, 0.f, 0.f};

    // staging: each wave DMAs 4 x 1KB chunks (A+B, 2 row-groups) per K-slice.
    const int lrow4 = lane >> 2;                       // row within 16-row group
    const int csrc  = (lane & 3) ^ ((lane >> 3) & 3);  // pre-swizzled src chunk

    auto stage = [&](int buf, int k0) {
        #pragma unroll
        for (int it = 0; it < 2; ++it) {
            const int w = wave * 2 + it;       // wave-load index 0..7
            const int r = w * 16 + lrow4;      // row 0..127
            glds16(xn + (size_t)(iBase + r) * D + k0 + csrc * 8,
                   &As[buf][w * 512]);
            glds16(xn + (size_t)(jBase + r) * D + k0 + csrc * 8,
                   &Bs[buf][w * 512]);
        }
    };

    // ds_read offsets (shorts): row rA = waveM*64 + tt*16 + l16, chunk = quad.
    const int swz  = (quad ^ ((l16 >> 1) & 3)) * 8;
    const int offA = (waveM * 64 + l16) * 32 + swz;
    const int offB = (waveN * 64 + l16) * 32 + swz;

    // prologue: tiles 0 and 1 in flight; wait only tile 0 (vmcnt back to 4)
    stage(0, 0);
    stage(1, 32);
    WAITCNT_VM4();
    __builtin_amdgcn_s_barrier();
    SCHED_FENCE();

    #pragma unroll
    for (int kt = 0; kt < 8; ++kt) {
        const int cb = kt % 3;
        // issue tile kt+2 FIRST: stays in flight across this step's barrier
        if (kt + 2 < 8) stage((kt + 2) % 3, (kt + 2) * 32);

        const unsigned short* Ap = &As[cb][0];
        const unsigned short* Bp = &Bs[cb][0];
        bf16x8 a[4], b[4];
        #pragma unroll
        for (int tt = 0; tt < 4; ++tt) {
            a[tt] = *(const bf16x8*)(Ap + offA + tt * 512);
            b[tt] = *(const bf16x8*)(Bp + offB + tt * 512);
        }
        __builtin_amdgcn_s_setprio(1);
        #pragma unroll
        for (int mt = 0; mt < 4; ++mt)
            #pragma unroll
            for (int nt = 0; nt < 4; ++nt)
                acc[mt][nt] = __builtin_amdgcn_mfma_f32_16x16x32_bf16(
                    a[mt], b[nt], acc[mt][nt], 0, 0, 0);
        __builtin_amdgcn_s_setprio(0);

        if (kt < 7) {
            SCHED_FENCE();
            WAITCNT_LGKM0();          // this wave's ds_reads of cb complete
            if (kt < 6) WAITCNT_VM4(); // tile kt+1 landed; kt+2 stays in flight
            else        WAITCNT_VM0(); // kt==6: last tile (7) must land
            __builtin_amdgcn_s_barrier();
            SCHED_FENCE();
        }
    }

    // Epilogue. C/D layout: col = l16, row = quad*4 + reg  [m89/m91]
    float rsum[4][4];
    float csum[4] = {0.f, 0.f, 0.f, 0.f};
    #pragma unroll
    for (int mt = 0; mt < 4; ++mt)
        #pragma unroll
        for (int r = 0; r < 4; ++r) rsum[mt][r] = 0.f;

    #pragma unroll
    for (int mt = 0; mt < 4; ++mt) {
        const int gi0 = iBase + waveM * 64 + mt * 16 + quad * 4;
        #pragma unroll
        for (int nt = 0; nt < 4; ++nt) {
            const int gj = jBase + waveN * 64 + nt * 16 + l16;
            #pragma unroll
            for (int r = 0; r < 4; ++r) {
                float e = __builtin_amdgcn_exp2f(acc[mt][nt][r] * TAU_INV_LOG2E);
                if (gi0 + r == gj) e = 0.0f;  // diagonal (only on diag tiles)
                rsum[mt][r] += e;
                csum[nt] += e;
            }
        }
    }
    // row partials -> slot 2*bj+waveN (each (row-block, slot) has exactly
    // one writer; see coverage proof in round-3 journal)
    {
        float* slot = prow + (size_t)(2 * bj + waveN) * N;
        #pragma unroll
        for (int mt = 0; mt < 4; ++mt) {
            const int gi0 = iBase + waveM * 64 + mt * 16 + quad * 4;
            #pragma unroll
            for (int r = 0; r < 4; ++r) {
                float s = rsum[mt][r];
                s += __shfl_xor(s, 1);
                s += __shfl_xor(s, 2);
                s += __shfl_xor(s, 4);
                s += __shfl_xor(s, 8);
                if (l16 == 0) slot[gi0 + r] = s;
            }
        }
    }
    // col partials (symmetry) -> slot 2*bi+waveM, off-diag tiles only
    if (!diag) {
        float* slot = prow + (size_t)(2 * bi + waveM) * N;
        #pragma unroll
        for (int nt = 0; nt < 4; ++nt) {
            float s = csum[nt];
            s += __shfl_xor(s, 16);
            s += __shfl_xor(s, 32);
            if (quad == 0)
                slot[jBase + waveN * 64 + nt * 16 + l16] = s;
        }
    }
}

// Kernel 3: rowsum_i = sum_p Prow[p][i]; loss += log(rowsum/(N-1)+eps)/N.
__global__ __launch_bounds__(256) void finalize_kernel(
    const float* __restrict__ prow, float* __restrict__ out, int N) {
    __shared__ float red[4];
    const int i = blockIdx.x * 256 + threadIdx.x;
    const float inv = 1.0f / (float)(N - 1);
    float s = 0.f;
    #pragma unroll 16
    for (int p = 0; p < 128; ++p) s += prow[(size_t)p * N + i];
    float acc = logf(fmaf(s, inv, EPS));
    acc += __shfl_xor(acc, 1);
    acc += __shfl_xor(acc, 2);
    acc += __shfl_xor(acc, 4);
    acc += __shfl_xor(acc, 8);
    acc += __shfl_xor(acc, 16);
    acc += __shfl_xor(acc, 32);
    const int wave = threadIdx.x >> 6;
    const int lane = threadIdx.x & 63;
    if (lane == 0) red[wave] = acc;
    __syncthreads();
    if (threadIdx.x == 0) {
        float total = red[0] + red[1] + red[2] + red[3];
        atomicAdd(out, total / (float)N);  // 32 atomics total
    }
}

extern "C" void kernel_launch(void* const* d_in, const int* in_sizes, int n_in,
                              void* d_out, int out_size, void* d_ws, size_t ws_size,
                              hipStream_t stream) {
    const float* x = (const float*)d_in[0];
    const int D = 256;
    const int N = in_sizes[0] / D;  // 8192

    unsigned short* xn = (unsigned short*)d_ws;  // N*D bf16 = 4 MB
    float* prow = (float*)((char*)d_ws + (size_t)N * D * sizeof(unsigned short));
    // Prow: 128 x N fp32 = 4 MB
    float* out = (float*)d_out;

    normalize_kernel<<<(N + 3) / 4, 256, 0, stream>>>(x, xn, out, N);

    const int B = N / 128;
    const int T = B * (B + 1) / 2;  // 2080 upper-triangle tiles
    gemm_exp_rowsum_kernel<<<T, 256, 0, stream>>>(xn, prow, N);

    finalize_kernel<<<N / 256, 256, 0, stream>>>(prow, out, N);
}